// Round 7
// baseline (511.387 us; speedup 1.0000x reference)
//
#include <hip/hip_runtime.h>
#include <cfloat>

// Problem constants (match reference setup_inputs)
#define BB 4
#define NQ 8192
#define NK 2048
#define CC 128
#define C4 (CC / 4)            // 32 float4 per feature row

#define QPB 64                 // queries per block
#define SPLITS 16              // key splits
#define KPS (NK / SPLITS)      // 128 keys per split
#define QPT 4                  // queries per thread
#define NTHR (QPB * SPLITS / QPT)   // 256 threads
#define RD_ROW 68              // 64 u32 + 4 pad

#define REP_FULL 8             // probe_full repetitions
#define REP_SCAN 16            // probe_scan repetitions

static __device__ __forceinline__ float fmed3(float a, float b, float c) {
    return __builtin_amdgcn_fmed3f(a, b, c);
}

// ---------------------------------------------------------------------------
// Kernel 1: pack keys as float4 {x, y, z, |k|^2} into workspace
// ---------------------------------------------------------------------------
__global__ __launch_bounds__(256) void pack_keys(
    const float* __restrict__ xyz_k, float4* __restrict__ keys)
{
    int i = blockIdx.x * 256 + threadIdx.x;   // flat b*NK + k
    if (i < BB * NK) {
        float x = xyz_k[i * 3 + 0];
        float y = xyz_k[i * 3 + 1];
        float z = xyz_k[i * 3 + 2];
        keys[i] = make_float4(x, y, z, fmaf(x, x, fmaf(y, y, z * z)));
    }
}

// ---------------------------------------------------------------------------
// Kernel 2: fused kNN + interpolation — IDENTICAL to round 6 (passing).
// ---------------------------------------------------------------------------
__global__ __launch_bounds__(NTHR, 2) void fp_main(
    const float*  __restrict__ xyz_q,
    const float4* __restrict__ keys,
    const float4* __restrict__ vk,
    float4*       __restrict__ out)
{
    __shared__ float4  ks[NK];              // 32 KiB
    __shared__ unsigned rd[QPB][RD_ROW];    // 17 KiB
    __shared__ float   sw[QPB][4];
    __shared__ int     si[QPB][4];

    const int b     = blockIdx.y;
    const int qbase = blockIdx.x * QPB;
    const int tid   = threadIdx.x;
    const int split = tid >> 4;
    const int g     = tid & 15;

    #pragma unroll
    for (int i = tid; i < NK; i += NTHR) ks[i] = keys[(size_t)b * NK + i];

    float ax[QPT], ay[QPT], az[QPT], qb_[QPT];
    #pragma unroll
    for (int qi = 0; qi < QPT; ++qi) {
        int q = qbase + g + 16 * qi;
        float qx = xyz_q[(b * NQ + q) * 3 + 0];
        float qy = xyz_q[(b * NQ + q) * 3 + 1];
        float qz = xyz_q[(b * NQ + q) * 3 + 2];
        ax[qi] = -2.0f * qx; ay[qi] = -2.0f * qy; az[qi] = -2.0f * qz;
        qb_[qi] = fmaf(qx, qx, fmaf(qy, qy, qz * qz)) + 1.0e-3f;
    }
    __syncthreads();

    const int kbeg = split * KPS;

    float u[QPT][4];
    #pragma unroll
    for (int qi = 0; qi < QPT; ++qi)
        u[qi][0] = u[qi][1] = u[qi][2] = u[qi][3] = FLT_MAX;

    #pragma unroll 8
    for (int j = 0; j < KPS; ++j) {
        float4 kk = ks[kbeg + j];
        unsigned kidx = (unsigned)(kbeg + j);
        #pragma unroll
        for (int qi = 0; qi < QPT; ++qi) {
            float t = fmaf(ax[qi], kk.x,
                      fmaf(ay[qi], kk.y,
                      fmaf(az[qi], kk.z, qb_[qi]))) + kk.w;
            float p = __uint_as_float((__float_as_uint(t) & 0xFFFFF800u) | kidx);
            u[qi][3] = fmed3(p, u[qi][2], u[qi][3]);
            u[qi][2] = fmed3(p, u[qi][1], u[qi][2]);
            u[qi][1] = fmed3(p, u[qi][0], u[qi][1]);
            u[qi][0] = fminf(u[qi][0], p);
        }
    }

    #pragma unroll
    for (int qi = 0; qi < QPT; ++qi) {
        int ql = g + 16 * qi;
        uint4 v = make_uint4(__float_as_uint(u[qi][0]), __float_as_uint(u[qi][1]),
                             __float_as_uint(u[qi][2]), __float_as_uint(u[qi][3]));
        *(uint4*)&rd[ql][split * 4] = v;
    }
    __syncthreads();

    if (tid < QPB) {
        const int ql = tid;
        float m[8];
        #pragma unroll
        for (int c = 0; c < 8; ++c) m[c] = FLT_MAX;
        #pragma unroll 4
        for (int i = 0; i < SPLITS; ++i) {
            uint4 v = *(const uint4*)&rd[ql][i * 4];
            unsigned vv[4] = { v.x, v.y, v.z, v.w };
            #pragma unroll
            for (int c = 0; c < 4; ++c) {
                float p = __uint_as_float(vv[c]);
                m[7] = fmed3(p, m[6], m[7]);
                m[6] = fmed3(p, m[5], m[6]);
                m[5] = fmed3(p, m[4], m[5]);
                m[4] = fmed3(p, m[3], m[4]);
                m[3] = fmed3(p, m[2], m[3]);
                m[2] = fmed3(p, m[1], m[2]);
                m[1] = fmed3(p, m[0], m[1]);
                m[0] = fminf(m[0], p);
            }
        }
        int q = qbase + ql;
        double qx = (double)xyz_q[(b * NQ + q) * 3 + 0];
        double qy = (double)xyz_q[(b * NQ + q) * 3 + 1];
        double qz = (double)xyz_q[(b * NQ + q) * 3 + 2];
        double M0 = DBL_MAX, M1 = DBL_MAX, M2 = DBL_MAX;
        #pragma unroll
        for (int c = 0; c < 8; ++c) {
            unsigned ki = __float_as_uint(m[c]) & 0x7FFu;
            float4 ka = ks[ki];
            double dx = qx - (double)ka.x;
            double dy = qy - (double)ka.y;
            double dz = qz - (double)ka.z;
            double dd = dx * dx + dy * dy + dz * dz;
            double x = __longlong_as_double(
                (long long)((((unsigned long long)__double_as_longlong(dd)) & ~0x7FFull)
                            | (unsigned long long)ki));
            double a1 = fmax(x, M1), a0 = fmax(x, M0);
            M2 = fmin(M2, a1);
            M1 = fmin(M1, a0);
            M0 = fmin(M0, x);
        }
        unsigned long long b0 = (unsigned long long)__double_as_longlong(M0);
        unsigned long long b1 = (unsigned long long)__double_as_longlong(M1);
        unsigned long long b2 = (unsigned long long)__double_as_longlong(M2);
        double e0 = __longlong_as_double((long long)(b0 & ~0x7FFull));
        double e1 = __longlong_as_double((long long)(b1 & ~0x7FFull));
        double e2 = __longlong_as_double((long long)(b2 & ~0x7FFull));
        e0 = fmax(e0, 1e-10);
        e1 = fmax(e1, 1e-10);
        e2 = fmax(e2, 1e-10);
        double w0 = 1.0 / e0, w1 = 1.0 / e1, w2 = 1.0 / e2;
        double s  = w0 + w1 + w2;
        sw[ql][0] = (float)(w0 / s);
        sw[ql][1] = (float)(w1 / s);
        sw[ql][2] = (float)(w2 / s);
        si[ql][0] = (int)(b0 & 0x7FFull);
        si[ql][1] = (int)(b1 & 0x7FFull);
        si[ql][2] = (int)(b2 & 0x7FFull);
    }
    __syncthreads();

    const float4* vb = vk + (size_t)b * NK * C4;
    float4* ob = out + ((size_t)b * NQ + qbase) * C4;
    #pragma unroll
    for (int r = 0; r < (QPB * C4) / NTHR; ++r) {
        int o  = r * NTHR + tid;
        int qq = o >> 5;
        int c4 = o & (C4 - 1);
        float w0 = sw[qq][0], w1 = sw[qq][1], w2 = sw[qq][2];
        int   j0 = si[qq][0], j1 = si[qq][1], j2 = si[qq][2];
        float4 v0 = vb[j0 * C4 + c4];
        float4 v1 = vb[j1 * C4 + c4];
        float4 v2 = vb[j2 * C4 + c4];
        float4 res;
        res.x = fmaf(w0, v0.x, fmaf(w1, v1.x, w2 * v2.x));
        res.y = fmaf(w0, v0.y, fmaf(w1, v1.y, w2 * v2.y));
        res.z = fmaf(w0, v0.z, fmaf(w1, v1.z, w2 * v2.z));
        res.w = fmaf(w0, v0.w, fmaf(w1, v1.w, w2 * v2.w));
        ob[o] = res;
    }
}

// ---------------------------------------------------------------------------
// PROBE A: full fp_main body x REP_FULL (query rotation per rep), out -> ws.
// dur/8 = true fp_main cost. Counters attribute the mixture.
// ---------------------------------------------------------------------------
__global__ __launch_bounds__(NTHR, 2) void probe_full(
    const float*  __restrict__ xyz_q,
    const float4* __restrict__ keys,
    const float4* __restrict__ vk,
    float4*       __restrict__ pout)
{
    __shared__ float4  ks[NK];
    __shared__ unsigned rd[QPB][RD_ROW];
    __shared__ float   sw[QPB][4];
    __shared__ int     si[QPB][4];

    const int b     = blockIdx.y;
    const int qbase = blockIdx.x * QPB;
    const int tid   = threadIdx.x;
    const int split = tid >> 4;
    const int g     = tid & 15;

    #pragma unroll
    for (int i = tid; i < NK; i += NTHR) ks[i] = keys[(size_t)b * NK + i];
    __syncthreads();

    const int kbeg = split * KPS;

    #pragma unroll 1
    for (int rep = 0; rep < REP_FULL; ++rep) {
        const int gr = (g + 5 * rep) & 15;   // rotate query assignment per rep

        float ax[QPT], ay[QPT], az[QPT], qb_[QPT];
        #pragma unroll
        for (int qi = 0; qi < QPT; ++qi) {
            int q = qbase + gr + 16 * qi;
            float qx = xyz_q[(b * NQ + q) * 3 + 0];
            float qy = xyz_q[(b * NQ + q) * 3 + 1];
            float qz = xyz_q[(b * NQ + q) * 3 + 2];
            ax[qi] = -2.0f * qx; ay[qi] = -2.0f * qy; az[qi] = -2.0f * qz;
            qb_[qi] = fmaf(qx, qx, fmaf(qy, qy, qz * qz)) + 1.0e-3f;
        }

        float u[QPT][4];
        #pragma unroll
        for (int qi = 0; qi < QPT; ++qi)
            u[qi][0] = u[qi][1] = u[qi][2] = u[qi][3] = FLT_MAX;

        #pragma unroll 8
        for (int j = 0; j < KPS; ++j) {
            float4 kk = ks[kbeg + j];
            unsigned kidx = (unsigned)(kbeg + j);
            #pragma unroll
            for (int qi = 0; qi < QPT; ++qi) {
                float t = fmaf(ax[qi], kk.x,
                          fmaf(ay[qi], kk.y,
                          fmaf(az[qi], kk.z, qb_[qi]))) + kk.w;
                float p = __uint_as_float((__float_as_uint(t) & 0xFFFFF800u) | kidx);
                u[qi][3] = fmed3(p, u[qi][2], u[qi][3]);
                u[qi][2] = fmed3(p, u[qi][1], u[qi][2]);
                u[qi][1] = fmed3(p, u[qi][0], u[qi][1]);
                u[qi][0] = fminf(u[qi][0], p);
            }
        }

        #pragma unroll
        for (int qi = 0; qi < QPT; ++qi) {
            int ql = gr + 16 * qi;
            uint4 v = make_uint4(__float_as_uint(u[qi][0]), __float_as_uint(u[qi][1]),
                                 __float_as_uint(u[qi][2]), __float_as_uint(u[qi][3]));
            *(uint4*)&rd[ql][split * 4] = v;
        }
        __syncthreads();

        if (tid < QPB) {
            const int ql = tid;
            float m[8];
            #pragma unroll
            for (int c = 0; c < 8; ++c) m[c] = FLT_MAX;
            #pragma unroll 4
            for (int i = 0; i < SPLITS; ++i) {
                uint4 v = *(const uint4*)&rd[ql][i * 4];
                unsigned vv[4] = { v.x, v.y, v.z, v.w };
                #pragma unroll
                for (int c = 0; c < 4; ++c) {
                    float p = __uint_as_float(vv[c]);
                    m[7] = fmed3(p, m[6], m[7]);
                    m[6] = fmed3(p, m[5], m[6]);
                    m[5] = fmed3(p, m[4], m[5]);
                    m[4] = fmed3(p, m[3], m[4]);
                    m[3] = fmed3(p, m[2], m[3]);
                    m[2] = fmed3(p, m[1], m[2]);
                    m[1] = fmed3(p, m[0], m[1]);
                    m[0] = fminf(m[0], p);
                }
            }
            int q = qbase + ql;
            double qx = (double)xyz_q[(b * NQ + q) * 3 + 0];
            double qy = (double)xyz_q[(b * NQ + q) * 3 + 1];
            double qz = (double)xyz_q[(b * NQ + q) * 3 + 2];
            double M0 = DBL_MAX, M1 = DBL_MAX, M2 = DBL_MAX;
            #pragma unroll
            for (int c = 0; c < 8; ++c) {
                unsigned ki = __float_as_uint(m[c]) & 0x7FFu;
                float4 ka = ks[ki];
                double dx = qx - (double)ka.x;
                double dy = qy - (double)ka.y;
                double dz = qz - (double)ka.z;
                double dd = dx * dx + dy * dy + dz * dz;
                double x = __longlong_as_double(
                    (long long)((((unsigned long long)__double_as_longlong(dd)) & ~0x7FFull)
                                | (unsigned long long)ki));
                double a1 = fmax(x, M1), a0 = fmax(x, M0);
                M2 = fmin(M2, a1);
                M1 = fmin(M1, a0);
                M0 = fmin(M0, x);
            }
            unsigned long long b0 = (unsigned long long)__double_as_longlong(M0);
            unsigned long long b1 = (unsigned long long)__double_as_longlong(M1);
            unsigned long long b2 = (unsigned long long)__double_as_longlong(M2);
            double e0 = __longlong_as_double((long long)(b0 & ~0x7FFull));
            double e1 = __longlong_as_double((long long)(b1 & ~0x7FFull));
            double e2 = __longlong_as_double((long long)(b2 & ~0x7FFull));
            e0 = fmax(e0, 1e-10);
            e1 = fmax(e1, 1e-10);
            e2 = fmax(e2, 1e-10);
            double w0 = 1.0 / e0, w1 = 1.0 / e1, w2 = 1.0 / e2;
            double s  = w0 + w1 + w2;
            sw[ql][0] = (float)(w0 / s);
            sw[ql][1] = (float)(w1 / s);
            sw[ql][2] = (float)(w2 / s);
            si[ql][0] = (int)(b0 & 0x7FFull);
            si[ql][1] = (int)(b1 & 0x7FFull);
            si[ql][2] = (int)(b2 & 0x7FFull);
        }
        __syncthreads();

        const float4* vb = vk + (size_t)b * NK * C4;
        float4* ob = pout + ((size_t)b * NQ + qbase) * C4;
        #pragma unroll
        for (int r = 0; r < (QPB * C4) / NTHR; ++r) {
            int o  = r * NTHR + tid;
            int qq = o >> 5;
            int c4 = o & (C4 - 1);
            float w0 = sw[qq][0], w1 = sw[qq][1], w2 = sw[qq][2];
            int   j0 = si[qq][0], j1 = si[qq][1], j2 = si[qq][2];
            float4 v0 = vb[j0 * C4 + c4];
            float4 v1 = vb[j1 * C4 + c4];
            float4 v2 = vb[j2 * C4 + c4];
            float4 res;
            res.x = fmaf(w0, v0.x, fmaf(w1, v1.x, w2 * v2.x));
            res.y = fmaf(w0, v0.y, fmaf(w1, v1.y, w2 * v2.y));
            res.z = fmaf(w0, v0.z, fmaf(w1, v1.z, w2 * v2.z));
            res.w = fmaf(w0, v0.w, fmaf(w1, v1.w, w2 * v2.w));
            ob[o] = res;
        }
        __syncthreads();
    }
}

// ---------------------------------------------------------------------------
// PROBE B: staging + phase-1 scan ONLY, x REP_SCAN (key-range rotation).
// dur/16 = true scan cost.
// ---------------------------------------------------------------------------
__global__ __launch_bounds__(NTHR, 2) void probe_scan(
    const float*  __restrict__ xyz_q,
    const float4* __restrict__ keys,
    uint4*        __restrict__ pout)
{
    __shared__ float4  ks[NK];
    __shared__ unsigned rd[QPB][RD_ROW];   // keep LDS footprint = fp_main

    const int b     = blockIdx.y;
    const int qbase = blockIdx.x * QPB;
    const int tid   = threadIdx.x;
    const int split = tid >> 4;
    const int g     = tid & 15;

    #pragma unroll
    for (int i = tid; i < NK; i += NTHR) ks[i] = keys[(size_t)b * NK + i];

    float ax[QPT], ay[QPT], az[QPT], qb_[QPT];
    #pragma unroll
    for (int qi = 0; qi < QPT; ++qi) {
        int q = qbase + g + 16 * qi;
        float qx = xyz_q[(b * NQ + q) * 3 + 0];
        float qy = xyz_q[(b * NQ + q) * 3 + 1];
        float qz = xyz_q[(b * NQ + q) * 3 + 2];
        ax[qi] = -2.0f * qx; ay[qi] = -2.0f * qy; az[qi] = -2.0f * qz;
        qb_[qi] = fmaf(qx, qx, fmaf(qy, qy, qz * qz)) + 1.0e-3f;
    }
    __syncthreads();

    float u[QPT][4];
    #pragma unroll
    for (int qi = 0; qi < QPT; ++qi)
        u[qi][0] = u[qi][1] = u[qi][2] = u[qi][3] = FLT_MAX;

    #pragma unroll 1
    for (int rep = 0; rep < REP_SCAN; ++rep) {
        const int kb2 = ((split + rep) & (SPLITS - 1)) * KPS;  // rotate range
        #pragma unroll 8
        for (int j = 0; j < KPS; ++j) {
            float4 kk = ks[kb2 + j];
            unsigned kidx = (unsigned)(kb2 + j);
            #pragma unroll
            for (int qi = 0; qi < QPT; ++qi) {
                float t = fmaf(ax[qi], kk.x,
                          fmaf(ay[qi], kk.y,
                          fmaf(az[qi], kk.z, qb_[qi]))) + kk.w;
                float p = __uint_as_float((__float_as_uint(t) & 0xFFFFF800u) | kidx);
                u[qi][3] = fmed3(p, u[qi][2], u[qi][3]);
                u[qi][2] = fmed3(p, u[qi][1], u[qi][2]);
                u[qi][1] = fmed3(p, u[qi][0], u[qi][1]);
                u[qi][0] = fminf(u[qi][0], p);
            }
        }
    }

    // keep results observable (and keep rd alive for LDS-footprint parity)
    rd[g][split] = __float_as_uint(u[0][0]);
    __syncthreads();
    size_t o = ((size_t)b * gridDim.x + blockIdx.x) * NTHR + tid;
    pout[o] = make_uint4(__float_as_uint(u[0][0]) ^ rd[g][split],
                         __float_as_uint(u[1][1]),
                         __float_as_uint(u[2][2]),
                         __float_as_uint(u[3][3]));
}

// ---------------------------------------------------------------------------
extern "C" void kernel_launch(void* const* d_in, const int* in_sizes, int n_in,
                              void* d_out, int out_size, void* d_ws, size_t ws_size,
                              hipStream_t stream)
{
    const float* xyz_q = (const float*)d_in[0];
    const float* xyz_k = (const float*)d_in[1];
    const float* v_k   = (const float*)d_in[2];

    char* ws = (char*)d_ws;
    float4* keys     = (float4*)ws;              // [0, 128 KiB)
    float4* pout_full = (float4*)(ws + (1u << 20));   // [1 MiB, 17 MiB)
    uint4*  pout_scan = (uint4*)(ws + (32u << 20));   // [32 MiB, ...)

    pack_keys<<<dim3((BB * NK + 255) / 256), dim3(256), 0, stream>>>(xyz_k, keys);
    fp_main<<<dim3(NQ / QPB, BB), dim3(NTHR), 0, stream>>>(
        xyz_q, keys, (const float4*)v_k, (float4*)d_out);
    probe_full<<<dim3(NQ / QPB, BB), dim3(NTHR), 0, stream>>>(
        xyz_q, keys, (const float4*)v_k, pout_full);
    probe_scan<<<dim3(NQ / QPB, BB), dim3(NTHR), 0, stream>>>(
        xyz_q, keys, pout_scan);
}

// Round 8
// 93.122 us; speedup vs baseline: 5.4916x; 5.4916x over previous
//
#include <hip/hip_runtime.h>
#include <cfloat>

// Problem constants (match reference setup_inputs)
#define BB 4
#define NQ 8192
#define NK 2048
#define CC 128
#define C4 (CC / 4)            // 32 float4 per feature row

#define QPB 64                 // queries per block
#define SPLITS 16              // key splits
#define KPS (NK / SPLITS)      // 128 keys per split
#define KPAD 2                 // +2 float4 per split: split stride 2080 B ->
                               // wave's 4 splits start on banks {0,8,16,24}
#define KROW (KPS + KPAD)      // 130
#define QPT 4                  // queries per thread
#define NTHR (QPB * SPLITS / QPT)   // 256 threads
#define RD_ROW 68              // 64 u32 + 4 pad

typedef float v2f __attribute__((ext_vector_type(2)));

static __device__ __forceinline__ float fmed3(float a, float b, float c) {
    return __builtin_amdgcn_fmed3f(a, b, c);
}

// ---------------------------------------------------------------------------
// Kernel 1: pack keys as float4 {x, y, z, |k|^2} into workspace
// ---------------------------------------------------------------------------
__global__ __launch_bounds__(256) void pack_keys(
    const float* __restrict__ xyz_k, float4* __restrict__ keys)
{
    int i = blockIdx.x * 256 + threadIdx.x;   // flat b*NK + k
    if (i < BB * NK) {
        float x = xyz_k[i * 3 + 0];
        float y = xyz_k[i * 3 + 1];
        float z = xyz_k[i * 3 + 2];
        keys[i] = make_float4(x, y, z, fmaf(x, x, fmaf(y, y, z * z)));
    }
}

// ---------------------------------------------------------------------------
// Kernel 2: fused kNN + interpolation, 4 queries/thread.
//   R7 probe: scan = 18.4 us of fp_main's ~28, with 4-way LDS bank conflicts
//   (SQ_LDS_BANK_CONFLICT=1.7e7; split stride 2048 B aliases bank quads) AND
//   VALU saturation. Fixes: (a) pad split stride to 2080 B -> the wave's 4
//   split addresses land on disjoint bank quads (conflict-free b128);
//   (b) packed-fp32 (v_pk_fma_f32) rank math, 2 queries per instruction.
//   grid = (NQ/QPB, BB) = 512 blocks, block = 256
// ---------------------------------------------------------------------------
__global__ __launch_bounds__(NTHR, 2) void fp_main(
    const float*  __restrict__ xyz_q,
    const float4* __restrict__ keys,
    const float4* __restrict__ vk,
    float4*       __restrict__ out)
{
    __shared__ float4  ks[SPLITS * KROW];   // 32.5 KiB, bank-staggered splits
    __shared__ unsigned rd[QPB][RD_ROW];    // 17 KiB: packed (dist|global idx)
    __shared__ float   sw[QPB][4];
    __shared__ int     si[QPB][4];

    const int b     = blockIdx.y;
    const int qbase = blockIdx.x * QPB;
    const int tid   = threadIdx.x;
    const int split = tid >> 4;             // 16 threads per split
    const int g     = tid & 15;             // query group: g, g+16, g+32, g+48

    // ---- stage packed keys into LDS (coalesced b128, 8 per thread) ----
    #pragma unroll
    for (int i = tid; i < NK; i += NTHR)
        ks[(i >> 7) * KROW + (i & (KPS - 1))] = keys[(size_t)b * NK + i];

    // ---- load 4 queries, rank coefficients packed in query pairs ----
    v2f AX[2], AY[2], AZ[2], QB[2];
    #pragma unroll
    for (int qi = 0; qi < QPT; ++qi) {
        int q = qbase + g + 16 * qi;
        float qx = xyz_q[(b * NQ + q) * 3 + 0];
        float qy = xyz_q[(b * NQ + q) * 3 + 1];
        float qz = xyz_q[(b * NQ + q) * 3 + 2];
        AX[qi >> 1][qi & 1] = -2.0f * qx;
        AY[qi >> 1][qi & 1] = -2.0f * qy;
        AZ[qi >> 1][qi & 1] = -2.0f * qz;
        // t = |q-k|^2 + 1e-3: strictly positive (packed-float order trick valid)
        QB[qi >> 1][qi & 1] = fmaf(qx, qx, fmaf(qy, qy, qz * qz)) + 1.0e-3f;
    }
    __syncthreads();

    const int kbase = split * KROW;         // LDS row base (staggered)
    const int kbeg  = split * KPS;          // global key index base

    // ---- phase 1: scan 128 keys x 4 queries, packed dist + med3 top-4 ----
    float u[QPT][4];
    #pragma unroll
    for (int qi = 0; qi < QPT; ++qi)
        u[qi][0] = u[qi][1] = u[qi][2] = u[qi][3] = FLT_MAX;

    #pragma unroll 8
    for (int j = 0; j < KPS; ++j) {
        float4 kk = ks[kbase + j];
        unsigned kidx = (unsigned)(kbeg + j);
        // packed rank: t = ax*kx + ay*ky + az*kz + (|q|^2+bias) + |k|^2
        v2f kx2 = { kk.x, kk.x }, ky2 = { kk.y, kk.y };
        v2f kz2 = { kk.z, kk.z }, kw2 = { kk.w, kk.w };
        #pragma unroll
        for (int pr = 0; pr < 2; ++pr) {
            v2f t2 = __builtin_elementwise_fma(AX[pr], kx2,
                     __builtin_elementwise_fma(AY[pr], ky2,
                     __builtin_elementwise_fma(AZ[pr], kz2, QB[pr]))) + kw2;
            #pragma unroll
            for (int h = 0; h < 2; ++h) {
                int qi = pr * 2 + h;
                float p = __uint_as_float(
                    (__float_as_uint(t2[h]) & 0xFFFFF800u) | kidx);
                u[qi][3] = fmed3(p, u[qi][2], u[qi][3]);
                u[qi][2] = fmed3(p, u[qi][1], u[qi][2]);
                u[qi][1] = fmed3(p, u[qi][0], u[qi][1]);
                u[qi][0] = fminf(u[qi][0], p);
            }
        }
    }

    // ---- write per-(query,split) top-4 as one uint4 each ----
    #pragma unroll
    for (int qi = 0; qi < QPT; ++qi) {
        int ql = g + 16 * qi;
        uint4 v = make_uint4(__float_as_uint(u[qi][0]), __float_as_uint(u[qi][1]),
                             __float_as_uint(u[qi][2]), __float_as_uint(u[qi][3]));
        *(uint4*)&rd[ql][split * 4] = v;
    }
    __syncthreads();

    // ---- phase 2: one wave merges 64 candidates -> top-8 -> fp64 refine ----
    if (tid < QPB) {
        const int ql = tid;
        float m[8];
        #pragma unroll
        for (int c = 0; c < 8; ++c) m[c] = FLT_MAX;
        #pragma unroll 4
        for (int i = 0; i < SPLITS; ++i) {
            uint4 v = *(const uint4*)&rd[ql][i * 4];
            unsigned vv[4] = { v.x, v.y, v.z, v.w };
            #pragma unroll
            for (int c = 0; c < 4; ++c) {
                float p = __uint_as_float(vv[c]);
                m[7] = fmed3(p, m[6], m[7]);
                m[6] = fmed3(p, m[5], m[6]);
                m[5] = fmed3(p, m[4], m[5]);
                m[4] = fmed3(p, m[3], m[4]);
                m[3] = fmed3(p, m[2], m[3]);
                m[2] = fmed3(p, m[1], m[2]);
                m[1] = fmed3(p, m[0], m[1]);
                m[0] = fminf(m[0], p);
            }
        }
        // exact fp64 refine of the 8 survivors (diff form: exact for fp32 in)
        int q = qbase + ql;
        double qx = (double)xyz_q[(b * NQ + q) * 3 + 0];
        double qy = (double)xyz_q[(b * NQ + q) * 3 + 1];
        double qz = (double)xyz_q[(b * NQ + q) * 3 + 2];
        double M0 = DBL_MAX, M1 = DBL_MAX, M2 = DBL_MAX;
        #pragma unroll
        for (int c = 0; c < 8; ++c) {
            unsigned ki = __float_as_uint(m[c]) & 0x7FFu;
            float4 ka = ks[(ki >> 7) * KROW + (ki & (KPS - 1))];
            double dx = qx - (double)ka.x;
            double dy = qy - (double)ka.y;
            double dz = qz - (double)ka.z;
            double dd = dx * dx + dy * dy + dz * dz;
            double x = __longlong_as_double(
                (long long)((((unsigned long long)__double_as_longlong(dd)) & ~0x7FFull)
                            | (unsigned long long)ki));
            double a1 = fmax(x, M1), a0 = fmax(x, M0);
            M2 = fmin(M2, a1);
            M1 = fmin(M1, a0);
            M0 = fmin(M0, x);
        }
        unsigned long long b0 = (unsigned long long)__double_as_longlong(M0);
        unsigned long long b1 = (unsigned long long)__double_as_longlong(M1);
        unsigned long long b2 = (unsigned long long)__double_as_longlong(M2);
        double e0 = __longlong_as_double((long long)(b0 & ~0x7FFull));
        double e1 = __longlong_as_double((long long)(b1 & ~0x7FFull));
        double e2 = __longlong_as_double((long long)(b2 & ~0x7FFull));
        e0 = fmax(e0, 1e-10);
        e1 = fmax(e1, 1e-10);
        e2 = fmax(e2, 1e-10);
        double w0 = 1.0 / e0, w1 = 1.0 / e1, w2 = 1.0 / e2;
        double s  = w0 + w1 + w2;
        sw[ql][0] = (float)(w0 / s);
        sw[ql][1] = (float)(w1 / s);
        sw[ql][2] = (float)(w2 / s);
        si[ql][0] = (int)(b0 & 0x7FFull);
        si[ql][1] = (int)(b1 & 0x7FFull);
        si[ql][2] = (int)(b2 & 0x7FFull);
    }
    __syncthreads();

    // ---- phase 3: gather + weighted sum, coalesced float4 writes ----
    const float4* vb = vk + (size_t)b * NK * C4;
    float4* ob = out + ((size_t)b * NQ + qbase) * C4;
    #pragma unroll
    for (int r = 0; r < (QPB * C4) / NTHR; ++r) {   // 8 iters
        int o  = r * NTHR + tid;
        int qq = o >> 5;          // C4 = 32 float4 per query
        int c4 = o & (C4 - 1);
        float w0 = sw[qq][0], w1 = sw[qq][1], w2 = sw[qq][2];
        int   j0 = si[qq][0], j1 = si[qq][1], j2 = si[qq][2];
        float4 v0 = vb[j0 * C4 + c4];
        float4 v1 = vb[j1 * C4 + c4];
        float4 v2 = vb[j2 * C4 + c4];
        float4 res;
        res.x = fmaf(w0, v0.x, fmaf(w1, v1.x, w2 * v2.x));
        res.y = fmaf(w0, v0.y, fmaf(w1, v1.y, w2 * v2.y));
        res.z = fmaf(w0, v0.z, fmaf(w1, v1.z, w2 * v2.z));
        res.w = fmaf(w0, v0.w, fmaf(w1, v1.w, w2 * v2.w));
        ob[o] = res;
    }
}

// ---------------------------------------------------------------------------
extern "C" void kernel_launch(void* const* d_in, const int* in_sizes, int n_in,
                              void* d_out, int out_size, void* d_ws, size_t ws_size,
                              hipStream_t stream)
{
    const float* xyz_q = (const float*)d_in[0];
    const float* xyz_k = (const float*)d_in[1];
    const float* v_k   = (const float*)d_in[2];

    float4* keys = (float4*)d_ws;   // BB*NK float4 = 128 KiB scratch

    pack_keys<<<dim3((BB * NK + 255) / 256), dim3(256), 0, stream>>>(xyz_k, keys);
    fp_main<<<dim3(NQ / QPB, BB), dim3(NTHR), 0, stream>>>(
        xyz_q, keys, (const float4*)v_k, (float4*)d_out);
}